// Round 7
// baseline (397.014 us; speedup 1.0000x reference)
//
#include <hip/hip_runtime.h>
#include <hip/hip_bf16.h>
#include <stdint.h>

// ETC encoder: B=2, SL=2048, RATIO=16, SG=128, S=2176, V=32000, D=512, H=8,
// HD=64, F=2048, L=2, NC=8.  All GEMMs run as bf16 MFMA (16x16x32), state
// kept in f32 for residual/LN precision.  N=512 GEMMs fuse the residual add
// (x += A@W^T + b) so no f32 tmp buffer round-trip exists.

namespace {

constexpr int kB  = 2;
constexpr int kSL = 2048;
constexpr int kSG = 128;
constexpr int kS  = 2176;
constexpr int kD  = 512;
constexpr int kH  = 8;
constexpr int kF  = 2048;
constexpr int kNC = 8;
constexpr int kM  = kB * kS;  // 4352 rows

typedef __bf16 bf16x8 __attribute__((ext_vector_type(8)));
typedef unsigned short u16x8 __attribute__((ext_vector_type(8)));
typedef float  f32x4  __attribute__((ext_vector_type(4)));
using bf16 = __hip_bfloat16;

__device__ __forceinline__ void gload16(const void* g, void* l) {
  __builtin_amdgcn_global_load_lds(
      (const __attribute__((address_space(1))) void*)g,
      (__attribute__((address_space(3))) void*)l, 16, 0, 0);
}

__device__ __forceinline__ float bfu2f(unsigned short u) {
  return __uint_as_float(((unsigned int)u) << 16);
}

// ---------------- f32 -> bf16 conversion of all 4 weight tensors ----------
__global__ __launch_bounds__(256) void cvt4_kernel(
    const float* __restrict__ s0, bf16* __restrict__ d0,
    const float* __restrict__ s1, bf16* __restrict__ d1,
    const float* __restrict__ s2, bf16* __restrict__ d2,
    const float* __restrict__ s3, bf16* __restrict__ d3) {
  constexpr int n0 = 2 * 1536 * 512 / 4;
  constexpr int n1 = 2 * 512 * 512 / 4;
  constexpr int n2 = 2 * 2048 * 512 / 4;
  constexpr int n3 = 2 * 512 * 2048 / 4;
  constexpr int total = n0 + n1 + n2 + n3;
  for (int i = blockIdx.x * 256 + threadIdx.x; i < total;
       i += gridDim.x * 256) {
    const float* src;
    bf16* dst;
    int j = i;
    if (j < n0) { src = s0; dst = d0; }
    else if ((j -= n0) < n1) { src = s1; dst = d1; }
    else if ((j -= n1) < n2) { src = s2; dst = d2; }
    else { j -= n2; src = s3; dst = d3; }
    float4 v = ((const float4*)src)[j];
    dst[j * 4 + 0] = __float2bfloat16(v.x);
    dst[j * 4 + 1] = __float2bfloat16(v.y);
    dst[j * 4 + 2] = __float2bfloat16(v.z);
    dst[j * 4 + 3] = __float2bfloat16(v.w);
  }
}

// ---------------- embedding gather (+ pad_glob in the extra block) --------
__global__ __launch_bounds__(128) void embed_kernel(
    const int* __restrict__ tok, const float* __restrict__ table,
    const float* __restrict__ gemb, float* __restrict__ x,
    bf16* __restrict__ x_bf, unsigned char* __restrict__ pad_long,
    unsigned char* __restrict__ pad_glob) {
  const int row = blockIdx.x;           // 0..4351 embed, 4352 pad_glob
  const int t = threadIdx.x;
  if (row == kM) {
    for (int i = t; i < kB * kSG; i += 128) {
      const int b = i >> 7, g = i & 127;
      bool all = true;
      for (int j = 0; j < 16; ++j)
        all = all && (tok[b * kSL + g * 16 + j] == 0);
      pad_glob[i] = all ? 1 : 0;
    }
    return;
  }
  const int b = row / kS, s = row % kS;
  const float* src;
  if (s < kSL) {
    const int tk = tok[b * kSL + s];
    if (t == 0) pad_long[b * kSL + s] = (tk == 0) ? 1 : 0;
    src = table + (size_t)tk * kD;
  } else {
    src = gemb;
  }
  float4 v = *(const float4*)(src + t * 4);
  *(float4*)(x + (size_t)row * kD + t * 4) = v;
  bf16* xb = x_bf + (size_t)row * kD + t * 4;
  xb[0] = __float2bfloat16(v.x);
  xb[1] = __float2bfloat16(v.y);
  xb[2] = __float2bfloat16(v.z);
  xb[3] = __float2bfloat16(v.w);
}

// ---------------- bf16 MFMA GEMM: C(M,N) = A(M,K) @ W(N,K)^T + bias --------
// OUT_MODE: 1 = bf16 out, 2 = bf16 out + relu
// 128x128 tile, 4 waves (2x2), each wave 64x64 via 4x4 16x16x32 frags.
template <int OUT_MODE>
__global__ __launch_bounds__(256) void gemm_bt(
    const bf16* __restrict__ A, const bf16* __restrict__ W,
    const float* __restrict__ bias, void* __restrict__ Cout,
    int M, int N, int K) {
  __shared__ __align__(16) bf16 As[128 * 32];
  __shared__ __align__(16) bf16 Bs[128 * 32];
  const int t = threadIdx.x;
  const int lane = t & 63;
  const int wid = t >> 6;
  const int wm = wid >> 1, wn = wid & 1;           // 2x2 waves, 64x64 each
  const int bm = blockIdx.y * 128, bn = blockIdx.x * 128;
  const int srow = t >> 2, scol = (t & 3) * 8;     // staging: 16B per thread

  f32x4 acc[4][4];
#pragma unroll
  for (int mi = 0; mi < 4; ++mi)
#pragma unroll
    for (int ni = 0; ni < 4; ++ni)
#pragma unroll
      for (int r = 0; r < 4; ++r) acc[mi][ni][r] = 0.f;

  const bf16* a0 = A + (size_t)(bm + srow) * K + scol;
  const bf16* a1 = a0 + (size_t)64 * K;
  const bf16* w0 = W + (size_t)(bn + srow) * K + scol;
  const bf16* w1p = w0 + (size_t)64 * K;

  for (int k0 = 0; k0 < K; k0 += 32) {
    gload16(a0 + k0, &As[t * 8]);
    gload16(a1 + k0, &As[2048 + t * 8]);
    gload16(w0 + k0, &Bs[t * 8]);
    gload16(w1p + k0, &Bs[2048 + t * 8]);
    __syncthreads();
    bf16x8 af[4], wf[4];
#pragma unroll
    for (int mi = 0; mi < 4; ++mi)
      af[mi] = *(const bf16x8*)&As[(wm * 64 + mi * 16 + (lane & 15)) * 32 +
                                   (lane >> 4) * 8];
#pragma unroll
    for (int ni = 0; ni < 4; ++ni)
      wf[ni] = *(const bf16x8*)&Bs[(wn * 64 + ni * 16 + (lane & 15)) * 32 +
                                   (lane >> 4) * 8];
#pragma unroll
    for (int mi = 0; mi < 4; ++mi)
#pragma unroll
      for (int ni = 0; ni < 4; ++ni)
        acc[mi][ni] = __builtin_amdgcn_mfma_f32_16x16x32_bf16(
            af[mi], wf[ni], acc[mi][ni], 0, 0, 0);
    __syncthreads();
  }

  const int lr = (lane >> 4) * 4;   // C/D: row = 4*(lane>>4)+r, col = lane&15
  const int lc = lane & 15;
#pragma unroll
  for (int ni = 0; ni < 4; ++ni) {
    const int col = bn + wn * 64 + ni * 16 + lc;
    const float bv = bias[col];
#pragma unroll
    for (int mi = 0; mi < 4; ++mi) {
#pragma unroll
      for (int r = 0; r < 4; ++r) {
        const int row = bm + wm * 64 + mi * 16 + lr + r;
        float v = acc[mi][ni][r] + bv;
        if (OUT_MODE == 2) v = fmaxf(v, 0.f);
        ((bf16*)Cout)[(size_t)row * N + col] = __float2bfloat16(v);
      }
    }
  }
}

// 128x64-tile GEMM with fused residual: X(M,512) += A(M,K) @ W(512,K)^T + b.
// 272 blocks, 8 MFMA : 3 gloads per K-iter, ~4 blocks/CU co-resident.
__global__ __launch_bounds__(256) void gemm_res(
    const bf16* __restrict__ A, const bf16* __restrict__ W,
    const float* __restrict__ bias, float* __restrict__ X, int K) {
  __shared__ __align__(16) bf16 As[128 * 32];
  __shared__ __align__(16) bf16 Bs[64 * 32];
  const int t = threadIdx.x;
  const int lane = t & 63;
  const int wid = t >> 6;
  const int wm = wid >> 1, wn = wid & 1;           // 2x2 waves, 64x32 each
  const int bm = blockIdx.y * 128, bn = blockIdx.x * 64;
  const int srow = t >> 2, scol = (t & 3) * 8;

  f32x4 acc[4][2];
#pragma unroll
  for (int mi = 0; mi < 4; ++mi)
#pragma unroll
    for (int ni = 0; ni < 2; ++ni)
#pragma unroll
      for (int r = 0; r < 4; ++r) acc[mi][ni][r] = 0.f;

  const bf16* a0 = A + (size_t)(bm + srow) * K + scol;
  const bf16* a1 = a0 + (size_t)64 * K;
  const bf16* w0 = W + (size_t)(bn + srow) * K + scol;

  for (int k0 = 0; k0 < K; k0 += 32) {
    gload16(a0 + k0, &As[t * 8]);
    gload16(a1 + k0, &As[2048 + t * 8]);
    gload16(w0 + k0, &Bs[t * 8]);
    __syncthreads();
    bf16x8 af[4], wf[2];
#pragma unroll
    for (int mi = 0; mi < 4; ++mi)
      af[mi] = *(const bf16x8*)&As[(wm * 64 + mi * 16 + (lane & 15)) * 32 +
                                   (lane >> 4) * 8];
#pragma unroll
    for (int ni = 0; ni < 2; ++ni)
      wf[ni] = *(const bf16x8*)&Bs[(wn * 32 + ni * 16 + (lane & 15)) * 32 +
                                   (lane >> 4) * 8];
#pragma unroll
    for (int mi = 0; mi < 4; ++mi)
#pragma unroll
      for (int ni = 0; ni < 2; ++ni)
        acc[mi][ni] = __builtin_amdgcn_mfma_f32_16x16x32_bf16(
            af[mi], wf[ni], acc[mi][ni], 0, 0, 0);
    __syncthreads();
  }

  const int lr = (lane >> 4) * 4;
  const int lc = lane & 15;
#pragma unroll
  for (int ni = 0; ni < 2; ++ni) {
    const int col = bn + wn * 32 + ni * 16 + lc;
    const float bv = bias[col];
#pragma unroll
    for (int mi = 0; mi < 4; ++mi) {
#pragma unroll
      for (int r = 0; r < 4; ++r) {
        const int row = bm + wm * 64 + mi * 16 + lr + r;
        float* xp = X + (size_t)row * kD + col;
        *xp = *xp + acc[mi][ni][r] + bv;
      }
    }
  }
}

// ---------------- sparse attention (merged long + global) ----------------
// blocks 0..2047: long queries, one block per (b,h,segment): 16 q x 17 k.
// blocks 2048..4095: global queries, one block per (b,h,g): 144 keys,
// key-parallel two-pass softmax (no serial exp chain).
__global__ __launch_bounds__(64) void attn_kernel(
    const bf16* __restrict__ qkv, const unsigned char* __restrict__ padl,
    const unsigned char* __restrict__ padg, bf16* __restrict__ o) {
  __shared__ float lds_buf[17 * 64 * 2];   // long: Ks|Vs.  glob: q|p.
  const int blk0 = blockIdx.x;
  const int g = blk0 & 127;
  const int h = (blk0 >> 7) & 7;
  const int b = (blk0 >> 10) & 1;
  const int t = threadIdx.x;

  if (blk0 < 2048) {
    // ---- long-query path ----
    float* Ks = lds_buf;
    float* Vs = lds_buf + 17 * 64;
    const int qi = t >> 2, part = t & 3;
    for (int e = t; e < 17 * 64; e += 64) {
      const int j = e >> 6, d = e & 63;
      const size_t row = (j < 16) ? (size_t)(b * kS + g * 16 + j)
                                  : (size_t)(b * kS + kSL + g);
      const bf16* base = qkv + row * (3 * kD) + h * 64 + d;
      Ks[e] = __bfloat162float(base[512]);
      Vs[e] = __bfloat162float(base[1024]);
    }
    __syncthreads();

    float qv[16];
    {
      const bf16* qb = qkv + (size_t)(b * kS + g * 16 + qi) * (3 * kD) +
                       h * 64 + part * 16;
#pragma unroll
      for (int d = 0; d < 16; ++d) qv[d] = __bfloat162float(qb[d]);
    }
    float sc[17];
#pragma unroll
    for (int j = 0; j < 17; ++j) {
      float s = 0.f;
      const float* kb = &Ks[j * 64 + part * 16];
#pragma unroll
      for (int d = 0; d < 16; ++d) s += qv[d] * kb[d];
      s += __shfl_xor(s, 1);
      s += __shfl_xor(s, 2);
      const bool pad = (j < 16) ? (padl[b * kSL + g * 16 + j] != 0)
                                : (padg[b * kSG + g] != 0);
      sc[j] = s * 0.125f + (pad ? -1e9f : 0.f);
    }
    float m = sc[0];
#pragma unroll
    for (int j = 1; j < 17; ++j) m = fmaxf(m, sc[j]);
    float l = 0.f;
#pragma unroll
    for (int j = 0; j < 17; ++j) {
      sc[j] = __expf(sc[j] - m);
      l += sc[j];
    }
    const float inv = 1.f / l;
    float ov[16];
#pragma unroll
    for (int d = 0; d < 16; ++d) ov[d] = 0.f;
#pragma unroll
    for (int j = 0; j < 17; ++j) {
      const float* vb = &Vs[j * 64 + part * 16];
#pragma unroll
      for (int d = 0; d < 16; ++d) ov[d] += sc[j] * vb[d];
    }
    bf16* ob = o + (size_t)(b * kS + g * 16 + qi) * kD + h * 64 + part * 16;
#pragma unroll
    for (int d = 0; d < 16; ++d) ob[d] = __float2bfloat16(ov[d] * inv);
  } else {
    // ---- global-query path ----
    float* q_lds = lds_buf;
    float* p_lds = lds_buf + 64;
    const size_t qrow = (size_t)(b * kS + kSL + g);
    const unsigned short* qkv_u = (const unsigned short*)qkv;
    q_lds[t] = bfu2f(qkv_u[qrow * 1536 + h * 64 + t]);
    __syncthreads();

    float sc[3];
#pragma unroll
    for (int c = 0; c < 3; ++c) {
      const int j = t + c * 64;
      float s = -3.0e38f;
      if (j < 144) {
        const size_t krow = (j < 16) ? (size_t)(b * kS + g * 16 + j)
                                     : (size_t)(b * kS + kSL + (j - 16));
        const u16x8* kb = (const u16x8*)(qkv_u + krow * 1536 + 512 + h * 64);
        float acc = 0.f;
#pragma unroll
        for (int d0 = 0; d0 < 8; ++d0) {
          u16x8 kv = kb[d0];
#pragma unroll
          for (int u = 0; u < 8; ++u) acc += q_lds[d0 * 8 + u] * bfu2f(kv[u]);
        }
        const bool pad = (j < 16) ? (padl[b * kSL + g * 16 + j] != 0)
                                  : (padg[b * kSG + (j - 16)] != 0);
        s = acc * 0.125f + (pad ? -1e9f : 0.f);
      }
      sc[c] = s;
    }
    float m = fmaxf(fmaxf(sc[0], sc[1]), sc[2]);
#pragma unroll
    for (int off = 1; off < 64; off <<= 1) m = fmaxf(m, __shfl_xor(m, off));
    float lsum = 0.f;
#pragma unroll
    for (int c = 0; c < 3; ++c) {
      const int j = t + c * 64;
      if (j < 144) {
        const float p = __expf(sc[c] - m);
        p_lds[j] = p;
        lsum += p;
      }
    }
#pragma unroll
    for (int off = 1; off < 64; off <<= 1) lsum += __shfl_xor(lsum, off);
    __syncthreads();
    const float inv = 1.f / lsum;

    float ov = 0.f;
#pragma unroll 8
    for (int j = 0; j < 144; ++j) {
      const size_t vrow = (j < 16) ? (size_t)(b * kS + g * 16 + j)
                                   : (size_t)(b * kS + kSL + (j - 16));
      ov += p_lds[j] * bfu2f(qkv_u[vrow * 1536 + 1024 + h * 64 + t]);
    }
    o[qrow * kD + h * 64 + t] = __float2bfloat16(ov * inv);
  }
}

// ---------------- LayerNorm in place on x (residual already fused) --------
__global__ __launch_bounds__(256) void ln_kernel(
    float* __restrict__ x, const float* __restrict__ gamma,
    const float* __restrict__ beta, bf16* __restrict__ x_bf) {
  const int row = blockIdx.x, t = threadIdx.x;
  const size_t base = (size_t)row * kD;
  float v0 = x[base + t];
  float v1 = x[base + t + 256];
  float s = v0 + v1, q = v0 * v0 + v1 * v1;
#pragma unroll
  for (int off = 32; off > 0; off >>= 1) {
    s += __shfl_down(s, off);
    q += __shfl_down(q, off);
  }
  __shared__ float rs[4], rq[4];
  const int wid = t >> 6;
  if ((t & 63) == 0) { rs[wid] = s; rq[wid] = q; }
  __syncthreads();
  const float S = rs[0] + rs[1] + rs[2] + rs[3];
  const float Q = rq[0] + rq[1] + rq[2] + rq[3];
  const float mean = S * (1.f / kD);
  const float var = Q * (1.f / kD) - mean * mean;
  const float inv = rsqrtf(var + 1e-5f);
  const float y0 = (v0 - mean) * inv * gamma[t] + beta[t];
  const float y1 = (v1 - mean) * inv * gamma[t + 256] + beta[t + 256];
  x[base + t] = y0;
  x[base + t + 256] = y1;
  x_bf[base + t] = __float2bfloat16(y0);
  x_bf[base + t + 256] = __float2bfloat16(y1);
}

// ---------------- masked mean-pool over globals: z[b][d] ----------------
// 64 blocks x 256 threads: block = (b, 16-d chunk); thread (gg,dl) sums 8
// g's; LDS tree-reduce over the 16 g-groups.
__global__ __launch_bounds__(256) void pool_kernel(
    const float* __restrict__ x, const unsigned char* __restrict__ padg,
    float* __restrict__ z) {
  const int b = blockIdx.x >> 5;
  const int d0 = (blockIdx.x & 31) * 16;
  const int gg = threadIdx.x >> 4, dl = threadIdx.x & 15;
  float acc = 0.f;
  int cnt = 0;
#pragma unroll
  for (int k = 0; k < 8; ++k) {
    const int g = k * 16 + gg;
    if (padg[b * kSG + g] == 0) {
      acc += x[(size_t)(b * kS + kSL + g) * kD + d0 + dl];
      ++cnt;
    }
  }
  __shared__ float red[256];
  __shared__ int redc[256];
  red[threadIdx.x] = acc;
  redc[threadIdx.x] = cnt;
  __syncthreads();
  for (int s = 8; s > 0; s >>= 1) {
    if (gg < s) {
      red[gg * 16 + dl] += red[(gg + s) * 16 + dl];
      redc[gg * 16 + dl] += redc[(gg + s) * 16 + dl];
    }
    __syncthreads();
  }
  if (gg == 0) z[b * kD + d0 + dl] = red[dl] / (float)redc[dl];
}

// ---------------- classifier layer 1: one wave per output dot ----------
__global__ __launch_bounds__(256) void cls1_kernel(
    const float* __restrict__ z, const float* __restrict__ w1,
    float* __restrict__ h1) {
  const int wv = (blockIdx.x * 256 + threadIdx.x) >> 6;  // 0..511
  const int lane = threadIdx.x & 63;
  const int b = wv >> 8, t = wv & 255;
  const float4* zp = (const float4*)(z + b * kD);
  const float4* wp = (const float4*)(w1 + (size_t)t * kD);
  float4 a0 = zp[lane * 2], a1 = zp[lane * 2 + 1];
  float4 b0 = wp[lane * 2], b1 = wp[lane * 2 + 1];
  float acc = a0.x * b0.x + a0.y * b0.y + a0.z * b0.z + a0.w * b0.w +
              a1.x * b1.x + a1.y * b1.y + a1.z * b1.z + a1.w * b1.w;
#pragma unroll
  for (int off = 32; off > 0; off >>= 1) acc += __shfl_down(acc, off);
  if (lane == 0) h1[wv] = fmaxf(acc, 0.f);
}

// ---------------- classifier layer 2: one wave per output ----------
__global__ __launch_bounds__(64) void cls2_kernel(
    const float* __restrict__ h1, const float* __restrict__ w2,
    float* __restrict__ out) {
  const int wv = blockIdx.x;   // 0..15 = b*8 + c
  const int lane = threadIdx.x;
  const int b = wv >> 3, c = wv & 7;
  float4 h4 = ((const float4*)(h1 + b * 256))[lane];
  float4 w4 = ((const float4*)(w2 + c * 256))[lane];
  float acc = h4.x * w4.x + h4.y * w4.y + h4.z * w4.z + h4.w * w4.w;
#pragma unroll
  for (int off = 32; off > 0; off >>= 1) acc += __shfl_down(acc, off);
  if (lane == 0) out[wv] = acc;
}

}  // namespace

extern "C" void kernel_launch(void* const* d_in, const int* in_sizes, int n_in,
                              void* d_out, int out_size, void* d_ws,
                              size_t ws_size, hipStream_t stream) {
  (void)in_sizes; (void)n_in; (void)out_size; (void)ws_size;
  const int*   token_ids    = (const int*)d_in[0];
  const float* embed_table  = (const float*)d_in[1];
  const float* global_embed = (const float*)d_in[2];
  const float* in_proj_w    = (const float*)d_in[3];
  const float* in_proj_b    = (const float*)d_in[4];
  const float* out_w        = (const float*)d_in[5];
  const float* out_b        = (const float*)d_in[6];
  const float* ln1_g        = (const float*)d_in[7];
  const float* ln1_b        = (const float*)d_in[8];
  const float* ln2_g        = (const float*)d_in[9];
  const float* ln2_b        = (const float*)d_in[10];
  const float* ff1_w        = (const float*)d_in[11];
  const float* ff1_b        = (const float*)d_in[12];
  const float* ff2_w        = (const float*)d_in[13];
  const float* ff2_b        = (const float*)d_in[14];
  const float* cls_w1       = (const float*)d_in[15];
  const float* cls_w2       = (const float*)d_in[16];
  float* out = (float*)d_out;

  char* ws = (char*)d_ws;
  size_t off = 0;
  auto alloc = [&](size_t bytes) -> void* {
    void* p = ws + off;
    off += (bytes + 255) & ~(size_t)255;
    return p;
  };
  float* x_f   = (float*)alloc((size_t)kM * kD * 4);
  bf16*  x_b   = (bf16*)alloc((size_t)kM * kD * 2);
  bf16*  qkv_b = (bf16*)alloc((size_t)kM * 3 * kD * 2);
  bf16*  o_b   = (bf16*)alloc((size_t)kM * kD * 2);
  bf16*  h_b   = (bf16*)alloc((size_t)kM * kF * 2);
  bf16*  wqkv  = (bf16*)alloc((size_t)2 * 1536 * 512 * 2);
  bf16*  wout  = (bf16*)alloc((size_t)2 * 512 * 512 * 2);
  bf16*  wff1  = (bf16*)alloc((size_t)2 * 2048 * 512 * 2);
  bf16*  wff2  = (bf16*)alloc((size_t)2 * 512 * 2048 * 2);
  unsigned char* padl = (unsigned char*)alloc(kB * kSL);
  unsigned char* padg = (unsigned char*)alloc(kB * kSG);
  float* z_f   = (float*)alloc((size_t)kB * kD * 4);
  float* h1_f  = (float*)alloc((size_t)kB * 256 * 4);

  cvt4_kernel<<<2048, 256, 0, stream>>>(in_proj_w, wqkv, out_w, wout,
                                        ff1_w, wff1, ff2_w, wff2);

  embed_kernel<<<kM + 1, 128, 0, stream>>>(token_ids, embed_table,
                                           global_embed, x_f, x_b, padl, padg);

  for (int l = 0; l < 2; ++l) {
    // QKV projection -> bf16
    gemm_bt<1><<<dim3(1536 / 128, kM / 128), 256, 0, stream>>>(
        x_b, wqkv + (size_t)l * 1536 * 512, in_proj_b + l * 1536, qkv_b,
        kM, 1536, 512);
    // sparse attention (merged long + global)
    attn_kernel<<<2 * kB * kH * kSG, 64, 0, stream>>>(qkv_b, padl, padg, o_b);
    // out projection fused with residual: x_f += o @ Wout^T + b
    gemm_res<<<dim3(512 / 64, kM / 128), 256, 0, stream>>>(
        o_b, wout + (size_t)l * 512 * 512, out_b + l * 512, x_f, 512);
    ln_kernel<<<kM, 256, 0, stream>>>(x_f, ln1_g + l * 512, ln1_b + l * 512,
                                      x_b);
    // FFN
    gemm_bt<2><<<dim3(2048 / 128, kM / 128), 256, 0, stream>>>(
        x_b, wff1 + (size_t)l * 2048 * 512, ff1_b + l * 2048, h_b,
        kM, 2048, 512);
    gemm_res<<<dim3(512 / 64, kM / 128), 256, 0, stream>>>(
        h_b, wff2 + (size_t)l * 512 * 2048, ff2_b + l * 512, x_f, 2048);
    ln_kernel<<<kM, 256, 0, stream>>>(x_f, ln2_g + l * 512, ln2_b + l * 512,
                                      x_b);
  }

  pool_kernel<<<kB * 32, 256, 0, stream>>>(x_f, padg, z_f);
  cls1_kernel<<<128, 256, 0, stream>>>(z_f, cls_w1, h1_f);
  cls2_kernel<<<16, 64, 0, stream>>>(h1_f, cls_w2, out);
}

// Round 8
// 375.260 us; speedup vs baseline: 1.0580x; 1.0580x over previous
//
#include <hip/hip_runtime.h>
#include <hip/hip_bf16.h>
#include <stdint.h>

// ETC encoder: B=2, SL=2048, RATIO=16, SG=128, S=2176, V=32000, D=512, H=8,
// HD=64, F=2048, L=2, NC=8.  All GEMMs run as bf16 MFMA (16x16x32), state
// kept in f32 for residual/LN precision.  N=512 GEMMs fuse the residual add
// (x += A@W^T + b).  All GEMM grids are 1-D with a bijective XCD swizzle so
// blocks sharing an A-panel land on the same XCD L2 (T1; grids % 8 == 0).

namespace {

constexpr int kB  = 2;
constexpr int kSL = 2048;
constexpr int kSG = 128;
constexpr int kS  = 2176;
constexpr int kD  = 512;
constexpr int kH  = 8;
constexpr int kF  = 2048;
constexpr int kNC = 8;
constexpr int kM  = kB * kS;  // 4352 rows

typedef __bf16 bf16x8 __attribute__((ext_vector_type(8)));
typedef unsigned short u16x8 __attribute__((ext_vector_type(8)));
typedef float  f32x4  __attribute__((ext_vector_type(4)));
using bf16 = __hip_bfloat16;

__device__ __forceinline__ void gload16(const void* g, void* l) {
  __builtin_amdgcn_global_load_lds(
      (const __attribute__((address_space(1))) void*)g,
      (__attribute__((address_space(3))) void*)l, 16, 0, 0);
}

__device__ __forceinline__ float bfu2f(unsigned short u) {
  return __uint_as_float(((unsigned int)u) << 16);
}

// XCD swizzle: hw block i -> logical tile; XCD c = i%8 gets the contiguous
// logical range [c*(T/8), (c+1)*(T/8)).  Requires T % 8 == 0.
__device__ __forceinline__ int xcd_swz(int i, int T) {
  return (i & 7) * (T >> 3) + (i >> 3);
}

// ---------------- f32 -> bf16 conversion of all 4 weight tensors ----------
__global__ __launch_bounds__(256) void cvt4_kernel(
    const float* __restrict__ s0, bf16* __restrict__ d0,
    const float* __restrict__ s1, bf16* __restrict__ d1,
    const float* __restrict__ s2, bf16* __restrict__ d2,
    const float* __restrict__ s3, bf16* __restrict__ d3) {
  constexpr int n0 = 2 * 1536 * 512 / 4;
  constexpr int n1 = 2 * 512 * 512 / 4;
  constexpr int n2 = 2 * 2048 * 512 / 4;
  constexpr int n3 = 2 * 512 * 2048 / 4;
  constexpr int total = n0 + n1 + n2 + n3;
  for (int i = blockIdx.x * 256 + threadIdx.x; i < total;
       i += gridDim.x * 256) {
    const float* src;
    bf16* dst;
    int j = i;
    if (j < n0) { src = s0; dst = d0; }
    else if ((j -= n0) < n1) { src = s1; dst = d1; }
    else if ((j -= n1) < n2) { src = s2; dst = d2; }
    else { j -= n2; src = s3; dst = d3; }
    float4 v = ((const float4*)src)[j];
    dst[j * 4 + 0] = __float2bfloat16(v.x);
    dst[j * 4 + 1] = __float2bfloat16(v.y);
    dst[j * 4 + 2] = __float2bfloat16(v.z);
    dst[j * 4 + 3] = __float2bfloat16(v.w);
  }
}

// ---------------- embedding gather (+ pad_glob in the extra block) --------
__global__ __launch_bounds__(128) void embed_kernel(
    const int* __restrict__ tok, const float* __restrict__ table,
    const float* __restrict__ gemb, float* __restrict__ x,
    bf16* __restrict__ x_bf, unsigned char* __restrict__ pad_long,
    unsigned char* __restrict__ pad_glob) {
  const int row = blockIdx.x;           // 0..4351 embed, 4352 pad_glob
  const int t = threadIdx.x;
  if (row == kM) {
    for (int i = t; i < kB * kSG; i += 128) {
      const int b = i >> 7, g = i & 127;
      bool all = true;
      for (int j = 0; j < 16; ++j)
        all = all && (tok[b * kSL + g * 16 + j] == 0);
      pad_glob[i] = all ? 1 : 0;
    }
    return;
  }
  const int b = row / kS, s = row % kS;
  const float* src;
  if (s < kSL) {
    const int tk = tok[b * kSL + s];
    if (t == 0) pad_long[b * kSL + s] = (tk == 0) ? 1 : 0;
    src = table + (size_t)tk * kD;
  } else {
    src = gemb;
  }
  float4 v = *(const float4*)(src + t * 4);
  *(float4*)(x + (size_t)row * kD + t * 4) = v;
  bf16* xb = x_bf + (size_t)row * kD + t * 4;
  xb[0] = __float2bfloat16(v.x);
  xb[1] = __float2bfloat16(v.y);
  xb[2] = __float2bfloat16(v.z);
  xb[3] = __float2bfloat16(v.w);
}

// ---------------- bf16 MFMA GEMM: C(M,N) = A(M,K) @ W(N,K)^T + bias --------
// OUT_MODE: 1 = bf16 out, 2 = bf16 out + relu
// 128x128 tile, 4 waves (2x2), 1-D grid + XCD swizzle (bn fastest in tile id
// so panel-sharing tiles are XCD-contiguous).
template <int OUT_MODE>
__global__ __launch_bounds__(256) void gemm_bt(
    const bf16* __restrict__ A, const bf16* __restrict__ W,
    const float* __restrict__ bias, void* __restrict__ Cout,
    int M, int N, int K) {
  __shared__ __align__(16) bf16 As[128 * 32];
  __shared__ __align__(16) bf16 Bs[128 * 32];
  const int t = threadIdx.x;
  const int lane = t & 63;
  const int wid = t >> 6;
  const int wm = wid >> 1, wn = wid & 1;           // 2x2 waves, 64x64 each
  const int NB = N >> 7;
  const int swz = xcd_swz(blockIdx.x, gridDim.x);
  const int bm = (swz / NB) * 128, bn = (swz % NB) * 128;
  const int srow = t >> 2, scol = (t & 3) * 8;     // staging: 16B per thread

  f32x4 acc[4][4];
#pragma unroll
  for (int mi = 0; mi < 4; ++mi)
#pragma unroll
    for (int ni = 0; ni < 4; ++ni)
#pragma unroll
      for (int r = 0; r < 4; ++r) acc[mi][ni][r] = 0.f;

  const bf16* a0 = A + (size_t)(bm + srow) * K + scol;
  const bf16* a1 = a0 + (size_t)64 * K;
  const bf16* w0 = W + (size_t)(bn + srow) * K + scol;
  const bf16* w1p = w0 + (size_t)64 * K;

  for (int k0 = 0; k0 < K; k0 += 32) {
    gload16(a0 + k0, &As[t * 8]);
    gload16(a1 + k0, &As[2048 + t * 8]);
    gload16(w0 + k0, &Bs[t * 8]);
    gload16(w1p + k0, &Bs[2048 + t * 8]);
    __syncthreads();
    bf16x8 af[4], wf[4];
#pragma unroll
    for (int mi = 0; mi < 4; ++mi)
      af[mi] = *(const bf16x8*)&As[(wm * 64 + mi * 16 + (lane & 15)) * 32 +
                                   (lane >> 4) * 8];
#pragma unroll
    for (int ni = 0; ni < 4; ++ni)
      wf[ni] = *(const bf16x8*)&Bs[(wn * 64 + ni * 16 + (lane & 15)) * 32 +
                                   (lane >> 4) * 8];
#pragma unroll
    for (int mi = 0; mi < 4; ++mi)
#pragma unroll
      for (int ni = 0; ni < 4; ++ni)
        acc[mi][ni] = __builtin_amdgcn_mfma_f32_16x16x32_bf16(
            af[mi], wf[ni], acc[mi][ni], 0, 0, 0);
    __syncthreads();
  }

  const int lr = (lane >> 4) * 4;   // C/D: row = 4*(lane>>4)+r, col = lane&15
  const int lc = lane & 15;
#pragma unroll
  for (int ni = 0; ni < 4; ++ni) {
    const int col = bn + wn * 64 + ni * 16 + lc;
    const float bv = bias[col];
#pragma unroll
    for (int mi = 0; mi < 4; ++mi) {
#pragma unroll
      for (int r = 0; r < 4; ++r) {
        const int row = bm + wm * 64 + mi * 16 + lr + r;
        float v = acc[mi][ni][r] + bv;
        if (OUT_MODE == 2) v = fmaxf(v, 0.f);
        ((bf16*)Cout)[(size_t)row * N + col] = __float2bfloat16(v);
      }
    }
  }
}

// 64x64-tile GEMM with fused residual: X(M,512) += A(M,K) @ W(512,K)^T + b.
// 544 blocks (~2.1/CU co-resident), XCD-swizzled.  4 waves (2x2), 32x32 each.
__global__ __launch_bounds__(256) void gemm_res(
    const bf16* __restrict__ A, const bf16* __restrict__ W,
    const float* __restrict__ bias, float* __restrict__ X, int K) {
  __shared__ __align__(16) bf16 As[64 * 32];
  __shared__ __align__(16) bf16 Bs[64 * 32];
  const int t = threadIdx.x;
  const int lane = t & 63;
  const int wid = t >> 6;
  const int wm = wid >> 1, wn = wid & 1;           // 2x2 waves, 32x32 each
  const int swz = xcd_swz(blockIdx.x, gridDim.x);  // 544 = 8 bn x 68 bm
  const int bm = (swz >> 3) * 64, bn = (swz & 7) * 64;
  const int srow = t >> 2, scol = (t & 3) * 8;

  f32x4 acc[2][2];
#pragma unroll
  for (int mi = 0; mi < 2; ++mi)
#pragma unroll
    for (int ni = 0; ni < 2; ++ni)
#pragma unroll
      for (int r = 0; r < 4; ++r) acc[mi][ni][r] = 0.f;

  const bf16* a0 = A + (size_t)(bm + srow) * K + scol;
  const bf16* w0 = W + (size_t)(bn + srow) * K + scol;

  for (int k0 = 0; k0 < K; k0 += 32) {
    gload16(a0 + k0, &As[t * 8]);
    gload16(w0 + k0, &Bs[t * 8]);
    __syncthreads();
    bf16x8 af[2], wf[2];
#pragma unroll
    for (int mi = 0; mi < 2; ++mi)
      af[mi] = *(const bf16x8*)&As[(wm * 32 + mi * 16 + (lane & 15)) * 32 +
                                   (lane >> 4) * 8];
#pragma unroll
    for (int ni = 0; ni < 2; ++ni)
      wf[ni] = *(const bf16x8*)&Bs[(wn * 32 + ni * 16 + (lane & 15)) * 32 +
                                   (lane >> 4) * 8];
#pragma unroll
    for (int mi = 0; mi < 2; ++mi)
#pragma unroll
      for (int ni = 0; ni < 2; ++ni)
        acc[mi][ni] = __builtin_amdgcn_mfma_f32_16x16x32_bf16(
            af[mi], wf[ni], acc[mi][ni], 0, 0, 0);
    __syncthreads();
  }

  const int lr = (lane >> 4) * 4;
  const int lc = lane & 15;
#pragma unroll
  for (int ni = 0; ni < 2; ++ni) {
    const int col = bn + wn * 32 + ni * 16 + lc;
    const float bv = bias[col];
#pragma unroll
    for (int mi = 0; mi < 2; ++mi) {
#pragma unroll
      for (int r = 0; r < 4; ++r) {
        const int row = bm + wm * 32 + mi * 16 + lr + r;
        float* xp = X + (size_t)row * kD + col;
        *xp = *xp + acc[mi][ni][r] + bv;
      }
    }
  }
}

// ---------------- sparse attention (merged long + global) ----------------
__global__ __launch_bounds__(64) void attn_kernel(
    const bf16* __restrict__ qkv, const unsigned char* __restrict__ padl,
    const unsigned char* __restrict__ padg, bf16* __restrict__ o) {
  __shared__ float lds_buf[17 * 64 * 2];   // long: Ks|Vs.  glob: q|p.
  const int blk0 = blockIdx.x;
  const int g = blk0 & 127;
  const int h = (blk0 >> 7) & 7;
  const int b = (blk0 >> 10) & 1;
  const int t = threadIdx.x;

  if (blk0 < 2048) {
    // ---- long-query path ----
    float* Ks = lds_buf;
    float* Vs = lds_buf + 17 * 64;
    const int qi = t >> 2, part = t & 3;
    for (int e = t; e < 17 * 64; e += 64) {
      const int j = e >> 6, d = e & 63;
      const size_t row = (j < 16) ? (size_t)(b * kS + g * 16 + j)
                                  : (size_t)(b * kS + kSL + g);
      const bf16* base = qkv + row * (3 * kD) + h * 64 + d;
      Ks[e] = __bfloat162float(base[512]);
      Vs[e] = __bfloat162float(base[1024]);
    }
    __syncthreads();

    float qv[16];
    {
      const bf16* qb = qkv + (size_t)(b * kS + g * 16 + qi) * (3 * kD) +
                       h * 64 + part * 16;
#pragma unroll
      for (int d = 0; d < 16; ++d) qv[d] = __bfloat162float(qb[d]);
    }
    float sc[17];
#pragma unroll
    for (int j = 0; j < 17; ++j) {
      float s = 0.f;
      const float* kb = &Ks[j * 64 + part * 16];
#pragma unroll
      for (int d = 0; d < 16; ++d) s += qv[d] * kb[d];
      s += __shfl_xor(s, 1);
      s += __shfl_xor(s, 2);
      const bool pad = (j < 16) ? (padl[b * kSL + g * 16 + j] != 0)
                                : (padg[b * kSG + g] != 0);
      sc[j] = s * 0.125f + (pad ? -1e9f : 0.f);
    }
    float m = sc[0];
#pragma unroll
    for (int j = 1; j < 17; ++j) m = fmaxf(m, sc[j]);
    float l = 0.f;
#pragma unroll
    for (int j = 0; j < 17; ++j) {
      sc[j] = __expf(sc[j] - m);
      l += sc[j];
    }
    const float inv = 1.f / l;
    float ov[16];
#pragma unroll
    for (int d = 0; d < 16; ++d) ov[d] = 0.f;
#pragma unroll
    for (int j = 0; j < 17; ++j) {
      const float* vb = &Vs[j * 64 + part * 16];
#pragma unroll
      for (int d = 0; d < 16; ++d) ov[d] += sc[j] * vb[d];
    }
    bf16* ob = o + (size_t)(b * kS + g * 16 + qi) * kD + h * 64 + part * 16;
#pragma unroll
    for (int d = 0; d < 16; ++d) ob[d] = __float2bfloat16(ov[d] * inv);
  } else {
    // ---- global-query path ----
    float* q_lds = lds_buf;
    float* p_lds = lds_buf + 64;
    const size_t qrow = (size_t)(b * kS + kSL + g);
    const unsigned short* qkv_u = (const unsigned short*)qkv;
    q_lds[t] = bfu2f(qkv_u[qrow * 1536 + h * 64 + t]);
    __syncthreads();

    float sc[3];
#pragma unroll
    for (int c = 0; c < 3; ++c) {
      const int j = t + c * 64;
      float s = -3.0e38f;
      if (j < 144) {
        const size_t krow = (j < 16) ? (size_t)(b * kS + g * 16 + j)
                                     : (size_t)(b * kS + kSL + (j - 16));
        const u16x8* kb = (const u16x8*)(qkv_u + krow * 1536 + 512 + h * 64);
        float acc = 0.f;
#pragma unroll
        for (int d0 = 0; d0 < 8; ++d0) {
          u16x8 kv = kb[d0];
#pragma unroll
          for (int u = 0; u < 8; ++u) acc += q_lds[d0 * 8 + u] * bfu2f(kv[u]);
        }
        const bool pad = (j < 16) ? (padl[b * kSL + g * 16 + j] != 0)
                                  : (padg[b * kSG + (j - 16)] != 0);
        s = acc * 0.125f + (pad ? -1e9f : 0.f);
      }
      sc[c] = s;
    }
    float m = fmaxf(fmaxf(sc[0], sc[1]), sc[2]);
#pragma unroll
    for (int off = 1; off < 64; off <<= 1) m = fmaxf(m, __shfl_xor(m, off));
    float lsum = 0.f;
#pragma unroll
    for (int c = 0; c < 3; ++c) {
      const int j = t + c * 64;
      if (j < 144) {
        const float p = __expf(sc[c] - m);
        p_lds[j] = p;
        lsum += p;
      }
    }
#pragma unroll
    for (int off = 1; off < 64; off <<= 1) lsum += __shfl_xor(lsum, off);
    __syncthreads();
    const float inv = 1.f / lsum;

    float ov = 0.f;
#pragma unroll 8
    for (int j = 0; j < 144; ++j) {
      const size_t vrow = (j < 16) ? (size_t)(b * kS + g * 16 + j)
                                   : (size_t)(b * kS + kSL + (j - 16));
      ov += p_lds[j] * bfu2f(qkv_u[vrow * 1536 + 1024 + h * 64 + t]);
    }
    o[qrow * kD + h * 64 + t] = __float2bfloat16(ov * inv);
  }
}

// ---------------- LayerNorm in place on x (residual already fused) --------
__global__ __launch_bounds__(256) void ln_kernel(
    float* __restrict__ x, const float* __restrict__ gamma,
    const float* __restrict__ beta, bf16* __restrict__ x_bf) {
  const int row = blockIdx.x, t = threadIdx.x;
  const size_t base = (size_t)row * kD;
  float v0 = x[base + t];
  float v1 = x[base + t + 256];
  float s = v0 + v1, q = v0 * v0 + v1 * v1;
#pragma unroll
  for (int off = 32; off > 0; off >>= 1) {
    s += __shfl_down(s, off);
    q += __shfl_down(q, off);
  }
  __shared__ float rs[4], rq[4];
  const int wid = t >> 6;
  if ((t & 63) == 0) { rs[wid] = s; rq[wid] = q; }
  __syncthreads();
  const float S = rs[0] + rs[1] + rs[2] + rs[3];
  const float Q = rq[0] + rq[1] + rq[2] + rq[3];
  const float mean = S * (1.f / kD);
  const float var = Q * (1.f / kD) - mean * mean;
  const float inv = rsqrtf(var + 1e-5f);
  const float y0 = (v0 - mean) * inv * gamma[t] + beta[t];
  const float y1 = (v1 - mean) * inv * gamma[t + 256] + beta[t + 256];
  x[base + t] = y0;
  x[base + t + 256] = y1;
  x_bf[base + t] = __float2bfloat16(y0);
  x_bf[base + t + 256] = __float2bfloat16(y1);
}

// ---------------- masked mean-pool over globals: z[b][d] ----------------
__global__ __launch_bounds__(256) void pool_kernel(
    const float* __restrict__ x, const unsigned char* __restrict__ padg,
    float* __restrict__ z) {
  const int b = blockIdx.x >> 5;
  const int d0 = (blockIdx.x & 31) * 16;
  const int gg = threadIdx.x >> 4, dl = threadIdx.x & 15;
  float acc = 0.f;
  int cnt = 0;
#pragma unroll
  for (int k = 0; k < 8; ++k) {
    const int g = k * 16 + gg;
    if (padg[b * kSG + g] == 0) {
      acc += x[(size_t)(b * kS + kSL + g) * kD + d0 + dl];
      ++cnt;
    }
  }
  __shared__ float red[256];
  __shared__ int redc[256];
  red[threadIdx.x] = acc;
  redc[threadIdx.x] = cnt;
  __syncthreads();
  for (int s = 8; s > 0; s >>= 1) {
    if (gg < s) {
      red[gg * 16 + dl] += red[(gg + s) * 16 + dl];
      redc[gg * 16 + dl] += redc[(gg + s) * 16 + dl];
    }
    __syncthreads();
  }
  if (gg == 0) z[b * kD + d0 + dl] = red[dl] / (float)redc[dl];
}

// ---------------- classifier layer 1: one wave per output dot ----------
__global__ __launch_bounds__(256) void cls1_kernel(
    const float* __restrict__ z, const float* __restrict__ w1,
    float* __restrict__ h1) {
  const int wv = (blockIdx.x * 256 + threadIdx.x) >> 6;  // 0..511
  const int lane = threadIdx.x & 63;
  const int b = wv >> 8, t = wv & 255;
  const float4* zp = (const float4*)(z + b * kD);
  const float4* wp = (const float4*)(w1 + (size_t)t * kD);
  float4 a0 = zp[lane * 2], a1 = zp[lane * 2 + 1];
  float4 b0 = wp[lane * 2], b1 = wp[lane * 2 + 1];
  float acc = a0.x * b0.x + a0.y * b0.y + a0.z * b0.z + a0.w * b0.w +
              a1.x * b1.x + a1.y * b1.y + a1.z * b1.z + a1.w * b1.w;
#pragma unroll
  for (int off = 32; off > 0; off >>= 1) acc += __shfl_down(acc, off);
  if (lane == 0) h1[wv] = fmaxf(acc, 0.f);
}

// ---------------- classifier layer 2: one wave per output ----------
__global__ __launch_bounds__(64) void cls2_kernel(
    const float* __restrict__ h1, const float* __restrict__ w2,
    float* __restrict__ out) {
  const int wv = blockIdx.x;   // 0..15 = b*8 + c
  const int lane = threadIdx.x;
  const int b = wv >> 3, c = wv & 7;
  float4 h4 = ((const float4*)(h1 + b * 256))[lane];
  float4 w4 = ((const float4*)(w2 + c * 256))[lane];
  float acc = h4.x * w4.x + h4.y * w4.y + h4.z * w4.z + h4.w * w4.w;
#pragma unroll
  for (int off = 32; off > 0; off >>= 1) acc += __shfl_down(acc, off);
  if (lane == 0) out[wv] = acc;
}

}  // namespace

extern "C" void kernel_launch(void* const* d_in, const int* in_sizes, int n_in,
                              void* d_out, int out_size, void* d_ws,
                              size_t ws_size, hipStream_t stream) {
  (void)in_sizes; (void)n_in; (void)out_size; (void)ws_size;
  const int*   token_ids    = (const int*)d_in[0];
  const float* embed_table  = (const float*)d_in[1];
  const float* global_embed = (const float*)d_in[2];
  const float* in_proj_w    = (const float*)d_in[3];
  const float* in_proj_b    = (const float*)d_in[4];
  const float* out_w        = (const float*)d_in[5];
  const float* out_b        = (const float*)d_in[6];
  const float* ln1_g        = (const float*)d_in[7];
  const float* ln1_b        = (const float*)d_in[8];
  const float* ln2_g        = (const float*)d_in[9];
  const float* ln2_b        = (const float*)d_in[10];
  const float* ff1_w        = (const float*)d_in[11];
  const float* ff1_b        = (const float*)d_in[12];
  const float* ff2_w        = (const float*)d_in[13];
  const float* ff2_b        = (const float*)d_in[14];
  const float* cls_w1       = (const float*)d_in[15];
  const float* cls_w2       = (const float*)d_in[16];
  float* out = (float*)d_out;

  char* ws = (char*)d_ws;
  size_t off = 0;
  auto alloc = [&](size_t bytes) -> void* {
    void* p = ws + off;
    off += (bytes + 255) & ~(size_t)255;
    return p;
  };
  float* x_f   = (float*)alloc((size_t)kM * kD * 4);
  bf16*  x_b   = (bf16*)alloc((size_t)kM * kD * 2);
  bf16*  qkv_b = (bf16*)alloc((size_t)kM * 3 * kD * 2);
  bf16*  o_b   = (bf16*)alloc((size_t)kM * kD * 2);
  bf16*  h_b   = (bf16*)alloc((size_t)kM * kF * 2);
  bf16*  wqkv  = (bf16*)alloc((size_t)2 * 1536 * 512 * 2);
  bf16*  wout  = (bf16*)alloc((size_t)2 * 512 * 512 * 2);
  bf16*  wff1  = (bf16*)alloc((size_t)2 * 2048 * 512 * 2);
  bf16*  wff2  = (bf16*)alloc((size_t)2 * 512 * 2048 * 2);
  unsigned char* padl = (unsigned char*)alloc(kB * kSL);
  unsigned char* padg = (unsigned char*)alloc(kB * kSG);
  float* z_f   = (float*)alloc((size_t)kB * kD * 4);
  float* h1_f  = (float*)alloc((size_t)kB * 256 * 4);

  cvt4_kernel<<<2048, 256, 0, stream>>>(in_proj_w, wqkv, out_w, wout,
                                        ff1_w, wff1, ff2_w, wff2);

  embed_kernel<<<kM + 1, 128, 0, stream>>>(token_ids, embed_table,
                                           global_embed, x_f, x_b, padl, padg);

  for (int l = 0; l < 2; ++l) {
    // QKV projection -> bf16   (grid 12*34 = 408, %8 == 0)
    gemm_bt<1><<<(1536 / 128) * (kM / 128), 256, 0, stream>>>(
        x_b, wqkv + (size_t)l * 1536 * 512, in_proj_b + l * 1536, qkv_b,
        kM, 1536, 512);
    // sparse attention (merged long + global)
    attn_kernel<<<2 * kB * kH * kSG, 64, 0, stream>>>(qkv_b, padl, padg, o_b);
    // out projection fused with residual: x_f += o @ Wout^T + b  (544 blocks)
    gemm_res<<<8 * (kM / 64), 256, 0, stream>>>(
        o_b, wout + (size_t)l * 512 * 512, out_b + l * 512, x_f, 512);
    ln_kernel<<<kM, 256, 0, stream>>>(x_f, ln1_g + l * 512, ln1_b + l * 512,
                                      x_b);
    // FFN   (grid 16*34 = 544)
    gemm_bt<2><<<(2048 / 128) * (kM / 128), 256, 0, stream>>>(
        x_b, wff1 + (size_t)l * 2048 * 512, ff1_b + l * 2048, h_b,
        kM, 2048, 512);
    gemm_res<<<8 * (kM / 64), 256, 0, stream>>>(
        h_b, wff2 + (size_t)l * 512 * 2048, ff2_b + l * 512, x_f, 2048);
    ln_kernel<<<kM, 256, 0, stream>>>(x_f, ln2_g + l * 512, ln2_b + l * 512,
                                      x_b);
  }

  pool_kernel<<<kB * 32, 256, 0, stream>>>(x_f, padg, z_f);
  cls1_kernel<<<128, 256, 0, stream>>>(z_f, cls_w1, h1_f);
  cls2_kernel<<<16, 64, 0, stream>>>(h1_f, cls_w2, out);
}

// Round 9
// 369.768 us; speedup vs baseline: 1.0737x; 1.0149x over previous
//
#include <hip/hip_runtime.h>
#include <hip/hip_bf16.h>
#include <stdint.h>

// ETC encoder: B=2, SL=2048, RATIO=16, SG=128, S=2176, V=32000, D=512, H=8,
// HD=64, F=2048, L=2, NC=8.  All GEMMs run as bf16 MFMA (16x16x32), state
// kept in f32 for residual/LN precision.  N=512 GEMMs fuse the residual add.
// GEMMs use a 2-deep double-buffered global_load_lds pipeline with counted
// s_waitcnt vmcnt(N) (T3/T4): loads for tile k+2 issue while tile k computes;
// the per-iteration vmcnt(0) barrier drain (the 7%-MfmaUtil stall) is gone.

namespace {

constexpr int kB  = 2;
constexpr int kSL = 2048;
constexpr int kSG = 128;
constexpr int kS  = 2176;
constexpr int kD  = 512;
constexpr int kH  = 8;
constexpr int kF  = 2048;
constexpr int kNC = 8;
constexpr int kM  = kB * kS;  // 4352 rows

typedef __bf16 bf16x8 __attribute__((ext_vector_type(8)));
typedef unsigned short u16x8 __attribute__((ext_vector_type(8)));
typedef float  f32x4  __attribute__((ext_vector_type(4)));
using bf16 = __hip_bfloat16;

__device__ __forceinline__ void gload16(const void* g, void* l) {
  __builtin_amdgcn_global_load_lds(
      (const __attribute__((address_space(1))) void*)g,
      (__attribute__((address_space(3))) void*)l, 16, 0, 0);
}

__device__ __forceinline__ float bfu2f(unsigned short u) {
  return __uint_as_float(((unsigned int)u) << 16);
}

// XCD swizzle: hw block i -> logical tile; XCD c = i%8 gets the contiguous
// logical range [c*(T/8), (c+1)*(T/8)).  Requires T % 8 == 0.
__device__ __forceinline__ int xcd_swz(int i, int T) {
  return (i & 7) * (T >> 3) + (i >> 3);
}

// ---------------- f32 -> bf16 conversion of all 4 weight tensors ----------
__global__ __launch_bounds__(256) void cvt4_kernel(
    const float* __restrict__ s0, bf16* __restrict__ d0,
    const float* __restrict__ s1, bf16* __restrict__ d1,
    const float* __restrict__ s2, bf16* __restrict__ d2,
    const float* __restrict__ s3, bf16* __restrict__ d3) {
  constexpr int n0 = 2 * 1536 * 512 / 4;
  constexpr int n1 = 2 * 512 * 512 / 4;
  constexpr int n2 = 2 * 2048 * 512 / 4;
  constexpr int n3 = 2 * 512 * 2048 / 4;
  constexpr int total = n0 + n1 + n2 + n3;
  for (int i = blockIdx.x * 256 + threadIdx.x; i < total;
       i += gridDim.x * 256) {
    const float* src;
    bf16* dst;
    int j = i;
    if (j < n0) { src = s0; dst = d0; }
    else if ((j -= n0) < n1) { src = s1; dst = d1; }
    else if ((j -= n1) < n2) { src = s2; dst = d2; }
    else { j -= n2; src = s3; dst = d3; }
    float4 v = ((const float4*)src)[j];
    dst[j * 4 + 0] = __float2bfloat16(v.x);
    dst[j * 4 + 1] = __float2bfloat16(v.y);
    dst[j * 4 + 2] = __float2bfloat16(v.z);
    dst[j * 4 + 3] = __float2bfloat16(v.w);
  }
}

// ---------------- embedding gather (+ pad_glob in the extra block) --------
__global__ __launch_bounds__(128) void embed_kernel(
    const int* __restrict__ tok, const float* __restrict__ table,
    const float* __restrict__ gemb, float* __restrict__ x,
    bf16* __restrict__ x_bf, unsigned char* __restrict__ pad_long,
    unsigned char* __restrict__ pad_glob) {
  const int row = blockIdx.x;           // 0..4351 embed, 4352 pad_glob
  const int t = threadIdx.x;
  if (row == kM) {
    for (int i = t; i < kB * kSG; i += 128) {
      const int b = i >> 7, g = i & 127;
      bool all = true;
      for (int j = 0; j < 16; ++j)
        all = all && (tok[b * kSL + g * 16 + j] == 0);
      pad_glob[i] = all ? 1 : 0;
    }
    return;
  }
  const int b = row / kS, s = row % kS;
  const float* src;
  if (s < kSL) {
    const int tk = tok[b * kSL + s];
    if (t == 0) pad_long[b * kSL + s] = (tk == 0) ? 1 : 0;
    src = table + (size_t)tk * kD;
  } else {
    src = gemb;
  }
  float4 v = *(const float4*)(src + t * 4);
  *(float4*)(x + (size_t)row * kD + t * 4) = v;
  bf16* xb = x_bf + (size_t)row * kD + t * 4;
  xb[0] = __float2bfloat16(v.x);
  xb[1] = __float2bfloat16(v.y);
  xb[2] = __float2bfloat16(v.z);
  xb[3] = __float2bfloat16(v.w);
}

// ---------------- bf16 MFMA GEMM: C(M,N) = A(M,K) @ W(N,K)^T + bias --------
// OUT_MODE: 1 = bf16 out, 2 = bf16 out + relu.  128x128 tile, 4 waves (2x2),
// 2-deep prefetch pipeline, counted vmcnt (4 loads/thread/stage).
template <int OUT_MODE>
__global__ __launch_bounds__(256) void gemm_bt(
    const bf16* __restrict__ A, const bf16* __restrict__ W,
    const float* __restrict__ bias, void* __restrict__ Cout,
    int M, int N, int K) {
  __shared__ __align__(16) bf16 As[3][128 * 32];
  __shared__ __align__(16) bf16 Bs[3][128 * 32];
  const int t = threadIdx.x;
  const int lane = t & 63;
  const int wid = t >> 6;
  const int wm = wid >> 1, wn = wid & 1;           // 2x2 waves, 64x64 each
  const int NB = N >> 7;
  const int swz = xcd_swz(blockIdx.x, gridDim.x);
  const int bm = (swz / NB) * 128, bn = (swz % NB) * 128;
  const int srow = t >> 2, scol = (t & 3) * 8;     // staging: 16B per thread

  f32x4 acc[4][4];
#pragma unroll
  for (int mi = 0; mi < 4; ++mi)
#pragma unroll
    for (int ni = 0; ni < 4; ++ni)
#pragma unroll
      for (int r = 0; r < 4; ++r) acc[mi][ni][r] = 0.f;

  const bf16* a0 = A + (size_t)(bm + srow) * K + scol;
  const bf16* a1 = a0 + (size_t)64 * K;
  const bf16* w0 = W + (size_t)(bn + srow) * K + scol;
  const bf16* w1p = w0 + (size_t)64 * K;

  auto stage = [&](int kt, int buf) {
    const int k0 = kt * 32;
    gload16(a0 + k0, &As[buf][t * 8]);
    gload16(a1 + k0, &As[buf][2048 + t * 8]);
    gload16(w0 + k0, &Bs[buf][t * 8]);
    gload16(w1p + k0, &Bs[buf][2048 + t * 8]);
  };

  const int nt = K >> 5;
  stage(0, 0);
  stage(1, 1);
  for (int kt = 0; kt < nt; ++kt) {
    const int cur = kt % 3;
    const int nxt = kt + 2;
    if (nxt < nt) {
      stage(nxt, nxt % 3);
      asm volatile("s_waitcnt vmcnt(8)" ::: "memory");   // cur tile landed
    } else if (kt + 1 < nt) {
      asm volatile("s_waitcnt vmcnt(4)" ::: "memory");
    } else {
      asm volatile("s_waitcnt vmcnt(0)" ::: "memory");
    }
    __builtin_amdgcn_s_barrier();    // all waves' cur-tile slices visible
    bf16x8 af[4], wf[4];
#pragma unroll
    for (int mi = 0; mi < 4; ++mi)
      af[mi] = *(const bf16x8*)&As[cur][(wm * 64 + mi * 16 + (lane & 15)) * 32 +
                                        (lane >> 4) * 8];
#pragma unroll
    for (int ni = 0; ni < 4; ++ni)
      wf[ni] = *(const bf16x8*)&Bs[cur][(wn * 64 + ni * 16 + (lane & 15)) * 32 +
                                        (lane >> 4) * 8];
#pragma unroll
    for (int mi = 0; mi < 4; ++mi)
#pragma unroll
      for (int ni = 0; ni < 4; ++ni)
        acc[mi][ni] = __builtin_amdgcn_mfma_f32_16x16x32_bf16(
            af[mi], wf[ni], acc[mi][ni], 0, 0, 0);
    __builtin_amdgcn_s_barrier();    // reads of cur done before its overwrite
  }

  const int lr = (lane >> 4) * 4;   // C/D: row = 4*(lane>>4)+r, col = lane&15
  const int lc = lane & 15;
#pragma unroll
  for (int ni = 0; ni < 4; ++ni) {
    const int col = bn + wn * 64 + ni * 16 + lc;
    const float bv = bias[col];
#pragma unroll
    for (int mi = 0; mi < 4; ++mi) {
#pragma unroll
      for (int r = 0; r < 4; ++r) {
        const int row = bm + wm * 64 + mi * 16 + lr + r;
        float v = acc[mi][ni][r] + bv;
        if (OUT_MODE == 2) v = fmaxf(v, 0.f);
        ((bf16*)Cout)[(size_t)row * N + col] = __float2bfloat16(v);
      }
    }
  }
}

// 64x64-tile GEMM with fused residual: X(M,512) += A(M,K) @ W(512,K)^T + b.
// 544 blocks, XCD-swizzled, 2-deep prefetch (2 loads/thread/stage).
__global__ __launch_bounds__(256) void gemm_res(
    const bf16* __restrict__ A, const bf16* __restrict__ W,
    const float* __restrict__ bias, float* __restrict__ X, int K) {
  __shared__ __align__(16) bf16 As[3][64 * 32];
  __shared__ __align__(16) bf16 Bs[3][64 * 32];
  const int t = threadIdx.x;
  const int lane = t & 63;
  const int wid = t >> 6;
  const int wm = wid >> 1, wn = wid & 1;           // 2x2 waves, 32x32 each
  const int swz = xcd_swz(blockIdx.x, gridDim.x);  // 544 = 8 bn x 68 bm
  const int bm = (swz >> 3) * 64, bn = (swz & 7) * 64;
  const int srow = t >> 2, scol = (t & 3) * 8;

  f32x4 acc[2][2];
#pragma unroll
  for (int mi = 0; mi < 2; ++mi)
#pragma unroll
    for (int ni = 0; ni < 2; ++ni)
#pragma unroll
      for (int r = 0; r < 4; ++r) acc[mi][ni][r] = 0.f;

  const bf16* a0 = A + (size_t)(bm + srow) * K + scol;
  const bf16* w0 = W + (size_t)(bn + srow) * K + scol;

  auto stage = [&](int kt, int buf) {
    const int k0 = kt * 32;
    gload16(a0 + k0, &As[buf][t * 8]);
    gload16(w0 + k0, &Bs[buf][t * 8]);
  };

  const int nt = K >> 5;
  stage(0, 0);
  stage(1, 1);
  for (int kt = 0; kt < nt; ++kt) {
    const int cur = kt % 3;
    const int nxt = kt + 2;
    if (nxt < nt) {
      stage(nxt, nxt % 3);
      asm volatile("s_waitcnt vmcnt(4)" ::: "memory");
    } else if (kt + 1 < nt) {
      asm volatile("s_waitcnt vmcnt(2)" ::: "memory");
    } else {
      asm volatile("s_waitcnt vmcnt(0)" ::: "memory");
    }
    __builtin_amdgcn_s_barrier();
    bf16x8 af[2], wf[2];
#pragma unroll
    for (int mi = 0; mi < 2; ++mi)
      af[mi] = *(const bf16x8*)&As[cur][(wm * 32 + mi * 16 + (lane & 15)) * 32 +
                                        (lane >> 4) * 8];
#pragma unroll
    for (int ni = 0; ni < 2; ++ni)
      wf[ni] = *(const bf16x8*)&Bs[cur][(wn * 32 + ni * 16 + (lane & 15)) * 32 +
                                        (lane >> 4) * 8];
#pragma unroll
    for (int mi = 0; mi < 2; ++mi)
#pragma unroll
      for (int ni = 0; ni < 2; ++ni)
        acc[mi][ni] = __builtin_amdgcn_mfma_f32_16x16x32_bf16(
            af[mi], wf[ni], acc[mi][ni], 0, 0, 0);
    __builtin_amdgcn_s_barrier();
  }

  const int lr = (lane >> 4) * 4;
  const int lc = lane & 15;
#pragma unroll
  for (int ni = 0; ni < 2; ++ni) {
    const int col = bn + wn * 32 + ni * 16 + lc;
    const float bv = bias[col];
#pragma unroll
    for (int mi = 0; mi < 2; ++mi) {
#pragma unroll
      for (int r = 0; r < 4; ++r) {
        const int row = bm + wm * 32 + mi * 16 + lr + r;
        float* xp = X + (size_t)row * kD + col;
        *xp = *xp + acc[mi][ni][r] + bv;
      }
    }
  }
}

// ---------------- sparse attention (merged long + global) ----------------
__global__ __launch_bounds__(64) void attn_kernel(
    const bf16* __restrict__ qkv, const unsigned char* __restrict__ padl,
    const unsigned char* __restrict__ padg, bf16* __restrict__ o) {
  __shared__ float lds_buf[17 * 64 * 2];   // long: Ks|Vs.  glob: q|p.
  const int blk0 = blockIdx.x;
  const int g = blk0 & 127;
  const int h = (blk0 >> 7) & 7;
  const int b = (blk0 >> 10) & 1;
  const int t = threadIdx.x;

  if (blk0 < 2048) {
    // ---- long-query path ----
    float* Ks = lds_buf;
    float* Vs = lds_buf + 17 * 64;
    const int qi = t >> 2, part = t & 3;
    for (int e = t; e < 17 * 64; e += 64) {
      const int j = e >> 6, d = e & 63;
      const size_t row = (j < 16) ? (size_t)(b * kS + g * 16 + j)
                                  : (size_t)(b * kS + kSL + g);
      const bf16* base = qkv + row * (3 * kD) + h * 64 + d;
      Ks[e] = __bfloat162float(base[512]);
      Vs[e] = __bfloat162float(base[1024]);
    }
    __syncthreads();

    float qv[16];
    {
      const bf16* qb = qkv + (size_t)(b * kS + g * 16 + qi) * (3 * kD) +
                       h * 64 + part * 16;
#pragma unroll
      for (int d = 0; d < 16; ++d) qv[d] = __bfloat162float(qb[d]);
    }
    float sc[17];
#pragma unroll
    for (int j = 0; j < 17; ++j) {
      float s = 0.f;
      const float* kb = &Ks[j * 64 + part * 16];
#pragma unroll
      for (int d = 0; d < 16; ++d) s += qv[d] * kb[d];
      s += __shfl_xor(s, 1);
      s += __shfl_xor(s, 2);
      const bool pad = (j < 16) ? (padl[b * kSL + g * 16 + j] != 0)
                                : (padg[b * kSG + g] != 0);
      sc[j] = s * 0.125f + (pad ? -1e9f : 0.f);
    }
    float m = sc[0];
#pragma unroll
    for (int j = 1; j < 17; ++j) m = fmaxf(m, sc[j]);
    float l = 0.f;
#pragma unroll
    for (int j = 0; j < 17; ++j) {
      sc[j] = __expf(sc[j] - m);
      l += sc[j];
    }
    const float inv = 1.f / l;
    float ov[16];
#pragma unroll
    for (int d = 0; d < 16; ++d) ov[d] = 0.f;
#pragma unroll
    for (int j = 0; j < 17; ++j) {
      const float* vb = &Vs[j * 64 + part * 16];
#pragma unroll
      for (int d = 0; d < 16; ++d) ov[d] += sc[j] * vb[d];
    }
    bf16* ob = o + (size_t)(b * kS + g * 16 + qi) * kD + h * 64 + part * 16;
#pragma unroll
    for (int d = 0; d < 16; ++d) ob[d] = __float2bfloat16(ov[d] * inv);
  } else {
    // ---- global-query path ----
    float* q_lds = lds_buf;
    float* p_lds = lds_buf + 64;
    const size_t qrow = (size_t)(b * kS + kSL + g);
    const unsigned short* qkv_u = (const unsigned short*)qkv;
    q_lds[t] = bfu2f(qkv_u[qrow * 1536 + h * 64 + t]);
    __syncthreads();

    float sc[3];
#pragma unroll
    for (int c = 0; c < 3; ++c) {
      const int j = t + c * 64;
      float s = -3.0e38f;
      if (j < 144) {
        const size_t krow = (j < 16) ? (size_t)(b * kS + g * 16 + j)
                                     : (size_t)(b * kS + kSL + (j - 16));
        const u16x8* kb = (const u16x8*)(qkv_u + krow * 1536 + 512 + h * 64);
        float acc = 0.f;
#pragma unroll
        for (int d0 = 0; d0 < 8; ++d0) {
          u16x8 kv = kb[d0];
#pragma unroll
          for (int u = 0; u < 8; ++u) acc += q_lds[d0 * 8 + u] * bfu2f(kv[u]);
        }
        const bool pad = (j < 16) ? (padl[b * kSL + g * 16 + j] != 0)
                                  : (padg[b * kSG + (j - 16)] != 0);
        s = acc * 0.125f + (pad ? -1e9f : 0.f);
      }
      sc[c] = s;
    }
    float m = fmaxf(fmaxf(sc[0], sc[1]), sc[2]);
#pragma unroll
    for (int off = 1; off < 64; off <<= 1) m = fmaxf(m, __shfl_xor(m, off));
    float lsum = 0.f;
#pragma unroll
    for (int c = 0; c < 3; ++c) {
      const int j = t + c * 64;
      if (j < 144) {
        const float p = __expf(sc[c] - m);
        p_lds[j] = p;
        lsum += p;
      }
    }
#pragma unroll
    for (int off = 1; off < 64; off <<= 1) lsum += __shfl_xor(lsum, off);
    __syncthreads();
    const float inv = 1.f / lsum;

    float ov = 0.f;
#pragma unroll 8
    for (int j = 0; j < 144; ++j) {
      const size_t vrow = (j < 16) ? (size_t)(b * kS + g * 16 + j)
                                   : (size_t)(b * kS + kSL + (j - 16));
      ov += p_lds[j] * bfu2f(qkv_u[vrow * 1536 + 1024 + h * 64 + t]);
    }
    o[qrow * kD + h * 64 + t] = __float2bfloat16(ov * inv);
  }
}

// ---------------- LayerNorm in place on x (residual already fused) --------
__global__ __launch_bounds__(256) void ln_kernel(
    float* __restrict__ x, const float* __restrict__ gamma,
    const float* __restrict__ beta, bf16* __restrict__ x_bf) {
  const int row = blockIdx.x, t = threadIdx.x;
  const size_t base = (size_t)row * kD;
  float v0 = x[base + t];
  float v1 = x[base + t + 256];
  float s = v0 + v1, q = v0 * v0 + v1 * v1;
#pragma unroll
  for (int off = 32; off > 0; off >>= 1) {
    s += __shfl_down(s, off);
    q += __shfl_down(q, off);
  }
  __shared__ float rs[4], rq[4];
  const int wid = t >> 6;
  if ((t & 63) == 0) { rs[wid] = s; rq[wid] = q; }
  __syncthreads();
  const float S = rs[0] + rs[1] + rs[2] + rs[3];
  const float Q = rq[0] + rq[1] + rq[2] + rq[3];
  const float mean = S * (1.f / kD);
  const float var = Q * (1.f / kD) - mean * mean;
  const float inv = rsqrtf(var + 1e-5f);
  const float y0 = (v0 - mean) * inv * gamma[t] + beta[t];
  const float y1 = (v1 - mean) * inv * gamma[t + 256] + beta[t + 256];
  x[base + t] = y0;
  x[base + t + 256] = y1;
  x_bf[base + t] = __float2bfloat16(y0);
  x_bf[base + t + 256] = __float2bfloat16(y1);
}

// ---------------- masked mean-pool over globals: z[b][d] ----------------
__global__ __launch_bounds__(256) void pool_kernel(
    const float* __restrict__ x, const unsigned char* __restrict__ padg,
    float* __restrict__ z) {
  const int b = blockIdx.x >> 5;
  const int d0 = (blockIdx.x & 31) * 16;
  const int gg = threadIdx.x >> 4, dl = threadIdx.x & 15;
  float acc = 0.f;
  int cnt = 0;
#pragma unroll
  for (int k = 0; k < 8; ++k) {
    const int g = k * 16 + gg;
    if (padg[b * kSG + g] == 0) {
      acc += x[(size_t)(b * kS + kSL + g) * kD + d0 + dl];
      ++cnt;
    }
  }
  __shared__ float red[256];
  __shared__ int redc[256];
  red[threadIdx.x] = acc;
  redc[threadIdx.x] = cnt;
  __syncthreads();
  for (int s = 8; s > 0; s >>= 1) {
    if (gg < s) {
      red[gg * 16 + dl] += red[(gg + s) * 16 + dl];
      redc[gg * 16 + dl] += redc[(gg + s) * 16 + dl];
    }
    __syncthreads();
  }
  if (gg == 0) z[b * kD + d0 + dl] = red[dl] / (float)redc[dl];
}

// ---------------- classifier layer 1: one wave per output dot ----------
__global__ __launch_bounds__(256) void cls1_kernel(
    const float* __restrict__ z, const float* __restrict__ w1,
    float* __restrict__ h1) {
  const int wv = (blockIdx.x * 256 + threadIdx.x) >> 6;  // 0..511
  const int lane = threadIdx.x & 63;
  const int b = wv >> 8, t = wv & 255;
  const float4* zp = (const float4*)(z + b * kD);
  const float4* wp = (const float4*)(w1 + (size_t)t * kD);
  float4 a0 = zp[lane * 2], a1 = zp[lane * 2 + 1];
  float4 b0 = wp[lane * 2], b1 = wp[lane * 2 + 1];
  float acc = a0.x * b0.x + a0.y * b0.y + a0.z * b0.z + a0.w * b0.w +
              a1.x * b1.x + a1.y * b1.y + a1.z * b1.z + a1.w * b1.w;
#pragma unroll
  for (int off = 32; off > 0; off >>= 1) acc += __shfl_down(acc, off);
  if (lane == 0) h1[wv] = fmaxf(acc, 0.f);
}

// ---------------- classifier layer 2: one wave per output ----------
__global__ __launch_bounds__(64) void cls2_kernel(
    const float* __restrict__ h1, const float* __restrict__ w2,
    float* __restrict__ out) {
  const int wv = blockIdx.x;   // 0..15 = b*8 + c
  const int lane = threadIdx.x;
  const int b = wv >> 3, c = wv & 7;
  float4 h4 = ((const float4*)(h1 + b * 256))[lane];
  float4 w4 = ((const float4*)(w2 + c * 256))[lane];
  float acc = h4.x * w4.x + h4.y * w4.y + h4.z * w4.z + h4.w * w4.w;
#pragma unroll
  for (int off = 32; off > 0; off >>= 1) acc += __shfl_down(acc, off);
  if (lane == 0) out[wv] = acc;
}

}  // namespace

extern "C" void kernel_launch(void* const* d_in, const int* in_sizes, int n_in,
                              void* d_out, int out_size, void* d_ws,
                              size_t ws_size, hipStream_t stream) {
  (void)in_sizes; (void)n_in; (void)out_size; (void)ws_size;
  const int*   token_ids    = (const int*)d_in[0];
  const float* embed_table  = (const float*)d_in[1];
  const float* global_embed = (const float*)d_in[2];
  const float* in_proj_w    = (const float*)d_in[3];
  const float* in_proj_b    = (const float*)d_in[4];
  const float* out_w        = (const float*)d_in[5];
  const float* out_b        = (const float*)d_in[6];
  const float* ln1_g        = (const float*)d_in[7];
  const float* ln1_b        = (const float*)d_in[8];
  const float* ln2_g        = (const float*)d_in[9];
  const float* ln2_b        = (const float*)d_in[10];
  const float* ff1_w        = (const float*)d_in[11];
  const float* ff1_b        = (const float*)d_in[12];
  const float* ff2_w        = (const float*)d_in[13];
  const float* ff2_b        = (const float*)d_in[14];
  const float* cls_w1       = (const float*)d_in[15];
  const float* cls_w2       = (const float*)d_in[16];
  float* out = (float*)d_out;

  char* ws = (char*)d_ws;
  size_t off = 0;
  auto alloc = [&](size_t bytes) -> void* {
    void* p = ws + off;
    off += (bytes + 255) & ~(size_t)255;
    return p;
  };
  float* x_f   = (float*)alloc((size_t)kM * kD * 4);
  bf16*  x_b   = (bf16*)alloc((size_t)kM * kD * 2);
  bf16*  qkv_b = (bf16*)alloc((size_t)kM * 3 * kD * 2);
  bf16*  o_b   = (bf16*)alloc((size_t)kM * kD * 2);
  bf16*  h_b   = (bf16*)alloc((size_t)kM * kF * 2);
  bf16*  wqkv  = (bf16*)alloc((size_t)2 * 1536 * 512 * 2);
  bf16*  wout  = (bf16*)alloc((size_t)2 * 512 * 512 * 2);
  bf16*  wff1  = (bf16*)alloc((size_t)2 * 2048 * 512 * 2);
  bf16*  wff2  = (bf16*)alloc((size_t)2 * 512 * 2048 * 2);
  unsigned char* padl = (unsigned char*)alloc(kB * kSL);
  unsigned char* padg = (unsigned char*)alloc(kB * kSG);
  float* z_f   = (float*)alloc((size_t)kB * kD * 4);
  float* h1_f  = (float*)alloc((size_t)kB * 256 * 4);

  cvt4_kernel<<<2048, 256, 0, stream>>>(in_proj_w, wqkv, out_w, wout,
                                        ff1_w, wff1, ff2_w, wff2);

  embed_kernel<<<kM + 1, 128, 0, stream>>>(token_ids, embed_table,
                                           global_embed, x_f, x_b, padl, padg);

  for (int l = 0; l < 2; ++l) {
    // QKV projection -> bf16   (grid 12*34 = 408, %8 == 0)
    gemm_bt<1><<<(1536 / 128) * (kM / 128), 256, 0, stream>>>(
        x_b, wqkv + (size_t)l * 1536 * 512, in_proj_b + l * 1536, qkv_b,
        kM, 1536, 512);
    // sparse attention (merged long + global)
    attn_kernel<<<2 * kB * kH * kSG, 64, 0, stream>>>(qkv_b, padl, padg, o_b);
    // out projection fused with residual: x_f += o @ Wout^T + b  (544 blocks)
    gemm_res<<<8 * (kM / 64), 256, 0, stream>>>(
        o_b, wout + (size_t)l * 512 * 512, out_b + l * 512, x_f, 512);
    ln_kernel<<<kM, 256, 0, stream>>>(x_f, ln1_g + l * 512, ln1_b + l * 512,
                                      x_b);
    // FFN   (grid 16*34 = 544)
    gemm_bt<2><<<(2048 / 128) * (kM / 128), 256, 0, stream>>>(
        x_b, wff1 + (size_t)l * 2048 * 512, ff1_b + l * 2048, h_b,
        kM, 2048, 512);
    gemm_res<<<8 * (kM / 64), 256, 0, stream>>>(
        h_b, wff2 + (size_t)l * 512 * 2048, ff2_b + l * 512, x_f, 2048);
    ln_kernel<<<kM, 256, 0, stream>>>(x_f, ln2_g + l * 512, ln2_b + l * 512,
                                      x_b);
  }

  pool_kernel<<<kB * 32, 256, 0, stream>>>(x_f, padg, z_f);
  cls1_kernel<<<128, 256, 0, stream>>>(z_f, cls_w1, h1_f);
  cls2_kernel<<<16, 64, 0, stream>>>(h1_f, cls_w2, out);
}